// Round 2
// baseline (2329.406 us; speedup 1.0000x reference)
//
#include <hip/hip_runtime.h>

#define T_SEQ 512
#define HID   50
#define HP    52      // padded hidden (multiple of 4, keeps float4 rows 16B-aligned)
#define BBLK  4       // batch rows per block
#define BLK   256

// waves_per_eu(2,2): force VGPR budget to 256 so the 156-float weight arrays
// stay register-resident. Round-1 evidence: VGPR_Count=128 + WRITE_SIZE=10.75MB
// (scratch spill stores; real output is 16KB) => compiler spilled weights.
__global__ __launch_bounds__(BLK)
__attribute__((amdgpu_waves_per_eu(2, 2)))
void lstm2_fused(const float* __restrict__ x,
                 const float* __restrict__ Wih0,
                 const float* __restrict__ Whh0,
                 const float* __restrict__ bih0,
                 const float* __restrict__ bhh0,
                 const float* __restrict__ Wih1,
                 const float* __restrict__ Whh1,
                 const float* __restrict__ bih1,
                 const float* __restrict__ bhh1,
                 const float* __restrict__ Wfc,
                 const float* __restrict__ bfc,
                 float* __restrict__ out)
{
    __shared__ __align__(16) float hA[BBLK][HP];       // layer0 hidden
    __shared__ __align__(16) float hB[BBLK][HP];       // layer1 hidden
    __shared__ __align__(16) float gs0[4][BBLK][HP];   // layer0 activated gates
    __shared__ __align__(16) float gs1[4][BBLK][HP];   // layer1 activated gates

    const int tid  = threadIdx.x;
    const int gt   = tid >> 6;        // wave id = gate type (i,f,g,o) in matvec phases
    const int lane = tid & 63;
    const int bb0  = blockIdx.x * BBLK;
    const bool on  = (lane < HID);
    const int  n   = on ? lane : (HID - 1);   // clamp idle lanes to a valid row
    const int  j   = gt * HID + n;            // gate output index in [0,200)

    // zero h buffers (pads stay zero forever; matched by zero weight pads)
    for (int i = tid; i < BBLK * HP; i += BLK) {
        (&hA[0][0])[i] = 0.0f;
        (&hB[0][0])[i] = 0.0f;
    }
    __syncthreads();

    // ---- time-invariant weights into registers (once) ----
    float w0[HP], w1a[HP], w1b[HP];
    #pragma unroll
    for (int k = 0; k < HP; ++k) { w0[k] = 0.f; w1a[k] = 0.f; w1b[k] = 0.f; }
    #pragma unroll
    for (int k = 0; k < HID; ++k) {
        w0 [k] = Whh0[j * HID + k];
        w1a[k] = Wih1[j * HID + k];
        w1b[k] = Whh1[j * HID + k];
    }
    const float wx  = Wih0[j];                // D == 1
    const float b0j = bih0[j] + bhh0[j];
    const float b1j = bih1[j] + bhh1[j];

    // branchless activation: y = sMul * sigmoid-core + sAdd  (gate 2 = tanh)
    const bool  tnh  = (gt == 2);
    const float sIn  = tnh ? -2.f : -1.f;
    const float sMul = tnh ?  2.f :  1.f;
    const float sAdd = tnh ? -1.f :  0.f;

    float cA = 0.f, cB = 0.f;   // cell states, owned by (wave=batch, lane=unit)

    const float* xrow = x + (long)bb0 * T_SEQ;

    for (int t = 0; t < T_SEQ; ++t) {
        // ================= layer 0: gates = b + Wih0*x_t + Whh0 @ hA =================
        float acc[BBLK];
        #pragma unroll
        for (int b = 0; b < BBLK; ++b)
            acc[b] = fmaf(wx, xrow[b * T_SEQ + t], b0j);

        #pragma unroll
        for (int k4 = 0; k4 < HP / 4; ++k4) {
            float4 hv[BBLK];
            #pragma unroll
            for (int b = 0; b < BBLK; ++b)
                hv[b] = *(const float4*)&hA[b][4 * k4];
            #pragma unroll
            for (int b = 0; b < BBLK; ++b) {
                acc[b] = fmaf(w0[4*k4+0], hv[b].x, acc[b]);
                acc[b] = fmaf(w0[4*k4+1], hv[b].y, acc[b]);
                acc[b] = fmaf(w0[4*k4+2], hv[b].z, acc[b]);
                acc[b] = fmaf(w0[4*k4+3], hv[b].w, acc[b]);
            }
        }

        #pragma unroll
        for (int b = 0; b < BBLK; ++b) {
            float s = 1.f / (1.f + __expf(sIn * acc[b]));
            if (on) gs0[gt][b][lane] = fmaf(sMul, s, sAdd);
        }
        __syncthreads();   // B1: gs0 complete

        // layer0 state update: wave -> batch row, lane -> hidden unit
        if (on) {
            float gi = gs0[0][gt][lane];
            float gf = gs0[1][gt][lane];
            float gg = gs0[2][gt][lane];
            float go = gs0[3][gt][lane];
            cA = fmaf(gf, cA, gi * gg);
            float th = 2.f / (1.f + __expf(-2.f * cA)) - 1.f;
            hA[gt][lane] = go * th;
        }
        __syncthreads();   // B2: hA complete

        // ================= layer 1: gates = b + Wih1 @ hA_new + Whh1 @ hB ============
        #pragma unroll
        for (int b = 0; b < BBLK; ++b) acc[b] = b1j;

        #pragma unroll
        for (int k4 = 0; k4 < HP / 4; ++k4) {
            float4 hv[BBLK];
            #pragma unroll
            for (int b = 0; b < BBLK; ++b)
                hv[b] = *(const float4*)&hA[b][4 * k4];
            #pragma unroll
            for (int b = 0; b < BBLK; ++b) {
                acc[b] = fmaf(w1a[4*k4+0], hv[b].x, acc[b]);
                acc[b] = fmaf(w1a[4*k4+1], hv[b].y, acc[b]);
                acc[b] = fmaf(w1a[4*k4+2], hv[b].z, acc[b]);
                acc[b] = fmaf(w1a[4*k4+3], hv[b].w, acc[b]);
            }
        }
        #pragma unroll
        for (int k4 = 0; k4 < HP / 4; ++k4) {
            float4 hv[BBLK];
            #pragma unroll
            for (int b = 0; b < BBLK; ++b)
                hv[b] = *(const float4*)&hB[b][4 * k4];
            #pragma unroll
            for (int b = 0; b < BBLK; ++b) {
                acc[b] = fmaf(w1b[4*k4+0], hv[b].x, acc[b]);
                acc[b] = fmaf(w1b[4*k4+1], hv[b].y, acc[b]);
                acc[b] = fmaf(w1b[4*k4+2], hv[b].z, acc[b]);
                acc[b] = fmaf(w1b[4*k4+3], hv[b].w, acc[b]);
            }
        }

        #pragma unroll
        for (int b = 0; b < BBLK; ++b) {
            float s = 1.f / (1.f + __expf(sIn * acc[b]));
            if (on) gs1[gt][b][lane] = fmaf(sMul, s, sAdd);
        }
        __syncthreads();   // B3: gs1 complete

        // layer1 state update (no trailing barrier: next use of hB is after B2(t+1),
        // next write of gs1 is after B3(t+1) — double-buffered gs removes the WAR)
        if (on) {
            float gi = gs1[0][gt][lane];
            float gf = gs1[1][gt][lane];
            float gg = gs1[2][gt][lane];
            float go = gs1[3][gt][lane];
            cB = fmaf(gf, cB, gi * gg);
            float th = 2.f / (1.f + __expf(-2.f * cB)) - 1.f;
            hB[gt][lane] = go * th;
        }
        __syncthreads();   // keep loop-carried hB/gs ordering sound for t+1 layer-1 reads
    }

    // ================= classifier: out[b][c] = hB[b] . Wfc[c] + bfc[c] ===============
    if (tid < BBLK * 2) {
        const int b = tid >> 1;
        const int c = tid & 1;
        float a = bfc[c];
        #pragma unroll
        for (int k = 0; k < HID; ++k)
            a = fmaf(Wfc[c * HID + k], hB[b][k], a);
        out[(bb0 + b) * 2 + c] = a;
    }
}

extern "C" void kernel_launch(void* const* d_in, const int* in_sizes, int n_in,
                              void* d_out, int out_size, void* d_ws, size_t ws_size,
                              hipStream_t stream) {
    const float* x    = (const float*)d_in[0];
    const float* Wih0 = (const float*)d_in[1];
    const float* Whh0 = (const float*)d_in[2];
    const float* bih0 = (const float*)d_in[3];
    const float* bhh0 = (const float*)d_in[4];
    const float* Wih1 = (const float*)d_in[5];
    const float* Whh1 = (const float*)d_in[6];
    const float* bih1 = (const float*)d_in[7];
    const float* bhh1 = (const float*)d_in[8];
    const float* Wfc  = (const float*)d_in[9];
    const float* bfc  = (const float*)d_in[10];
    float* out = (float*)d_out;

    const int B = in_sizes[0] / T_SEQ;     // D == 1
    const int grid = B / BBLK;             // 2048/4 = 512 blocks

    hipLaunchKernelGGL(lstm2_fused, dim3(grid), dim3(BLK), 0, stream,
                       x, Wih0, Whh0, bih0, bhh0, Wih1, Whh1, bih1, bhh1,
                       Wfc, bfc, out);
}

// Round 3
// 1955.516 us; speedup vs baseline: 1.1912x; 1.1912x over previous
//
#include <hip/hip_runtime.h>

#define T_SEQ 512
#define HID   50
#define HP    52      // padded hidden (multiple of 4; row stride 208B = 16B-aligned)
#define BBLK  4       // batch rows per block
#define BLK   256

typedef float v4f __attribute__((ext_vector_type(4)));
typedef float v2f __attribute__((ext_vector_type(2)));

#define REP13(F) F(0) F(1) F(2) F(3) F(4) F(5) F(6) F(7) F(8) F(9) F(10) F(11) F(12)

// Named SSA weight registers — NO arrays/allocas, so promotion to VGPRs is
// unconditional (R1/R2 evidence: float w[52] arrays stayed in scratch:
// VGPR_Count=128 + 12.7MB WRITE_SIZE of alloca traffic; SROA can't promote
// runtime-indexed arrays before unrolling).
#define DECLW(i) v4f w0_##i, w1a_##i, w1b_##i;

// element loads with compile-time pad (4*12+2,3 are the k=50,51 pads -> 0)
#define LDW(i) \
  w0_##i  = (v4f){ pW0 [4*i], pW0 [4*i+1], (4*i+2<HID)?pW0 [4*i+2]:0.f, (4*i+3<HID)?pW0 [4*i+3]:0.f }; \
  w1a_##i = (v4f){ pW1a[4*i], pW1a[4*i+1], (4*i+2<HID)?pW1a[4*i+2]:0.f, (4*i+3<HID)?pW1a[4*i+3]:0.f }; \
  w1b_##i = (v4f){ pW1b[4*i], pW1b[4*i+1], (4*i+2<HID)?pW1b[4*i+2]:0.f, (4*i+3<HID)?pW1b[4*i+3]:0.f };

// one K-chunk of the matvec for all 4 batch rows; float2 halves ->
// v_pk_fma_f32 (packed fp32 = 2 FMAs/instr, the path to 157TF vector fp32)
#define MVSTEP(W, H, i) { \
    const v4f h0 = *(const v4f*)&H[0][4*(i)]; \
    const v4f h1 = *(const v4f*)&H[1][4*(i)]; \
    const v4f h2 = *(const v4f*)&H[2][4*(i)]; \
    const v4f h3 = *(const v4f*)&H[3][4*(i)]; \
    acc0 = __builtin_elementwise_fma(W##_##i.lo, h0.lo, acc0); \
    acc1 = __builtin_elementwise_fma(W##_##i.lo, h1.lo, acc1); \
    acc2 = __builtin_elementwise_fma(W##_##i.lo, h2.lo, acc2); \
    acc3 = __builtin_elementwise_fma(W##_##i.lo, h3.lo, acc3); \
    acc0 = __builtin_elementwise_fma(W##_##i.hi, h0.hi, acc0); \
    acc1 = __builtin_elementwise_fma(W##_##i.hi, h1.hi, acc1); \
    acc2 = __builtin_elementwise_fma(W##_##i.hi, h2.hi, acc2); \
    acc3 = __builtin_elementwise_fma(W##_##i.hi, h3.hi, acc3); }

#define MV_W0(i)  MVSTEP(w0,  hA, i)
#define MV_W1A(i) MVSTEP(w1a, hA, i)
#define MV_W1B(i) MVSTEP(w1b, hB, i)

__global__ __launch_bounds__(BLK)
__attribute__((amdgpu_waves_per_eu(2)))   // cap 256 VGPRs: 2 waves/SIMD = 8 waves/CU, matches 2-blocks/CU grid
void lstm2_fused(const float* __restrict__ x,
                 const float* __restrict__ Wih0,
                 const float* __restrict__ Whh0,
                 const float* __restrict__ bih0,
                 const float* __restrict__ bhh0,
                 const float* __restrict__ Wih1,
                 const float* __restrict__ Whh1,
                 const float* __restrict__ bih1,
                 const float* __restrict__ bhh1,
                 const float* __restrict__ Wfc,
                 const float* __restrict__ bfc,
                 float* __restrict__ out)
{
    __shared__ __align__(16) float hA[BBLK][HP];       // layer0 hidden
    __shared__ __align__(16) float hB[BBLK][HP];       // layer1 hidden
    __shared__ __align__(16) float gs0[4][BBLK][HP];   // layer0 activated gates
    __shared__ __align__(16) float gs1[4][BBLK][HP];   // layer1 activated gates

    const int tid  = threadIdx.x;
    const int gt   = tid >> 6;        // wave id = gate type (i,f,g,o) in matvec phases
    const int lane = tid & 63;
    const int bb0  = blockIdx.x * BBLK;
    const bool on  = (lane < HID);
    const int  n   = on ? lane : (HID - 1);   // clamp idle lanes
    const int  j   = gt * HID + n;            // gate output index in [0,200)

    for (int i = tid; i < BBLK * HP; i += BLK) {
        (&hA[0][0])[i] = 0.0f;
        (&hB[0][0])[i] = 0.0f;
    }
    __syncthreads();

    const float* pW0  = Whh0 + j * HID;
    const float* pW1a = Wih1 + j * HID;
    const float* pW1b = Whh1 + j * HID;

    DECLW(0) DECLW(1) DECLW(2) DECLW(3) DECLW(4) DECLW(5) DECLW(6)
    DECLW(7) DECLW(8) DECLW(9) DECLW(10) DECLW(11) DECLW(12)
    REP13(LDW)

    const float wx  = Wih0[j];                // D == 1
    const float b0j = bih0[j] + bhh0[j];
    const float b1j = bih1[j] + bhh1[j];

    // branchless activation constants (gate 2 = tanh via 2*sigmoid(2x)-1)
    const bool  tnh  = (gt == 2);
    const float sIn  = tnh ? -2.f : -1.f;
    const float sMul = tnh ?  2.f :  1.f;
    const float sAdd = tnh ? -1.f :  0.f;

    float cA = 0.f, cB = 0.f;   // cell states, owned by (wave=batch, lane=unit)

    const float* xrow = x + (long)bb0 * T_SEQ;

    #pragma clang loop unroll(disable)
    for (int t = 0; t < T_SEQ; ++t) {
        // ========= layer 0: g = b0 + Wih0*x_t + Whh0 @ hA =========
        v2f acc0 = (v2f){fmaf(wx, xrow[0 * T_SEQ + t], b0j), 0.f};
        v2f acc1 = (v2f){fmaf(wx, xrow[1 * T_SEQ + t], b0j), 0.f};
        v2f acc2 = (v2f){fmaf(wx, xrow[2 * T_SEQ + t], b0j), 0.f};
        v2f acc3 = (v2f){fmaf(wx, xrow[3 * T_SEQ + t], b0j), 0.f};
        REP13(MV_W0)

        {
            float g0 = acc0.x + acc0.y, g1 = acc1.x + acc1.y;
            float g2 = acc2.x + acc2.y, g3 = acc3.x + acc3.y;
            float s0 = __builtin_amdgcn_rcpf(1.f + __expf(sIn * g0));
            float s1 = __builtin_amdgcn_rcpf(1.f + __expf(sIn * g1));
            float s2 = __builtin_amdgcn_rcpf(1.f + __expf(sIn * g2));
            float s3 = __builtin_amdgcn_rcpf(1.f + __expf(sIn * g3));
            if (on) {
                gs0[gt][0][lane] = fmaf(sMul, s0, sAdd);
                gs0[gt][1][lane] = fmaf(sMul, s1, sAdd);
                gs0[gt][2][lane] = fmaf(sMul, s2, sAdd);
                gs0[gt][3][lane] = fmaf(sMul, s3, sAdd);
            }
        }
        __syncthreads();   // B1: gs0 visible

        // layer0 state update: wave -> batch row, lane -> hidden unit
        if (on) {
            float gi = gs0[0][gt][lane];
            float gf = gs0[1][gt][lane];
            float gg = gs0[2][gt][lane];
            float go = gs0[3][gt][lane];
            cA = fmaf(gf, cA, gi * gg);
            float th = fmaf(2.f, __builtin_amdgcn_rcpf(1.f + __expf(-2.f * cA)), -1.f);
            hA[gt][lane] = go * th;
        }
        __syncthreads();   // B2: hA(t) visible

        // ========= layer 1: g = b1 + Wih1 @ hA + Whh1 @ hB =========
        acc0 = (v2f){b1j, 0.f};
        acc1 = (v2f){b1j, 0.f};
        acc2 = (v2f){b1j, 0.f};
        acc3 = (v2f){b1j, 0.f};
        REP13(MV_W1A)
        REP13(MV_W1B)

        {
            float g0 = acc0.x + acc0.y, g1 = acc1.x + acc1.y;
            float g2 = acc2.x + acc2.y, g3 = acc3.x + acc3.y;
            float s0 = __builtin_amdgcn_rcpf(1.f + __expf(sIn * g0));
            float s1 = __builtin_amdgcn_rcpf(1.f + __expf(sIn * g1));
            float s2 = __builtin_amdgcn_rcpf(1.f + __expf(sIn * g2));
            float s3 = __builtin_amdgcn_rcpf(1.f + __expf(sIn * g3));
            if (on) {
                gs1[gt][0][lane] = fmaf(sMul, s0, sAdd);
                gs1[gt][1][lane] = fmaf(sMul, s1, sAdd);
                gs1[gt][2][lane] = fmaf(sMul, s2, sAdd);
                gs1[gt][3][lane] = fmaf(sMul, s3, sAdd);
            }
        }
        __syncthreads();   // B3: gs1 visible

        // layer1 state update (no trailing barrier: hB written here is next
        // read at L1-matvec(t+1), which is beyond B1(t+1)+B2(t+1); gs0/gs1
        // WAR hazards are covered by the two intervening barriers)
        if (on) {
            float gi = gs1[0][gt][lane];
            float gf = gs1[1][gt][lane];
            float gg = gs1[2][gt][lane];
            float go = gs1[3][gt][lane];
            cB = fmaf(gf, cB, gi * gg);
            float th = fmaf(2.f, __builtin_amdgcn_rcpf(1.f + __expf(-2.f * cB)), -1.f);
            hB[gt][lane] = go * th;
        }
    }
    __syncthreads();   // hB final visible to classifier lanes

    // ========= classifier: out[b][c] = hB[b] . Wfc[c] + bfc[c] =========
    if (tid < BBLK * 2) {
        const int b = tid >> 1;
        const int c = tid & 1;
        float a = bfc[c];
        #pragma unroll
        for (int k = 0; k < HID; ++k)
            a = fmaf(Wfc[c * HID + k], hB[b][k], a);
        out[(bb0 + b) * 2 + c] = a;
    }
}

extern "C" void kernel_launch(void* const* d_in, const int* in_sizes, int n_in,
                              void* d_out, int out_size, void* d_ws, size_t ws_size,
                              hipStream_t stream) {
    const float* x    = (const float*)d_in[0];
    const float* Wih0 = (const float*)d_in[1];
    const float* Whh0 = (const float*)d_in[2];
    const float* bih0 = (const float*)d_in[3];
    const float* bhh0 = (const float*)d_in[4];
    const float* Wih1 = (const float*)d_in[5];
    const float* Whh1 = (const float*)d_in[6];
    const float* bih1 = (const float*)d_in[7];
    const float* bhh1 = (const float*)d_in[8];
    const float* Wfc  = (const float*)d_in[9];
    const float* bfc  = (const float*)d_in[10];
    float* out = (float*)d_out;

    const int B = in_sizes[0] / T_SEQ;     // D == 1
    const int grid = B / BBLK;             // 2048/4 = 512 blocks

    hipLaunchKernelGGL(lstm2_fused, dim3(grid), dim3(BLK), 0, stream,
                       x, Wih0, Whh0, bih0, bhh0, Wih1, Whh1, bih1, bhh1,
                       Wfc, bfc, out);
}